// Round 8
// baseline (40.563 us; speedup 1.0000x reference)
//
#include <hip/hip_runtime.h>
#include <stdint.h>

// C51 categorical projection — reg-staged pipeline, prefetch distance 2.
//
// R7 lessons: nt stores changed nothing (FETCH still 54MB) — cache-policy
// lever dead. Occupancy (6/8/12 blk/CU), depth (2.67 vs 4 iters), staging
// style: all flat at ~40-41us = 62% of copy ceiling. Residual theory:
// exposed load latency — each wave issues its 13 loads, computes ~0.8us,
// then stalls on those same loads (per-request latency under load >> one
// compute phase). This round: prefetch distance 2 (stgA/stgB, statically
// named register sets per rule #20), doubling the latency budget to two
// compute+writeout phases. Single variable vs R7; nt stores kept.
//
// Per half-body (tile tk via stgX):
//   1. ds_write_b128 x13: stgX -> LDS         (compiler-counted vmcnt wait)
//   2. issue global_load_dwordx4 x13 + r/done for tile tk+2G -> stgX
//   3. p[51] <- LDS; zero tile (13 b128); stream-emit bins (monotone l_j)
//   4. writeout: 13 x (ds_read_b128 -> nt global_store_dwordx4)
// Single-wave blocks: DS pipe in-order per wave -> no barriers anywhere.

#define ATOMS 51
#define RPB   64
#define THREADS 64
#define TILE_FLOATS (RPB * ATOMS)          // 3264 floats = 13056 B
#define TILE_VECS   (TILE_FLOATS / 4)      // 816
#define VEC_ITERS   ((TILE_VECS + THREADS - 1) / THREADS)  // 13 (last iter: 48 lanes)
#define GRID_MAX 2048                      // 8192 tiles / 2048 = exactly 4 iters/block

typedef float vfloat4 __attribute__((ext_vector_type(4)));

__device__ __forceinline__ void load_tile(const float* __restrict__ prob,
                                          int tile, int t, vfloat4* stg) {
    const vfloat4* gsrc = reinterpret_cast<const vfloat4*>(prob + (size_t)tile * TILE_FLOATS);
    #pragma unroll
    for (int i = 0; i < VEC_ITERS; ++i) {
        const int v = i * THREADS + t;
        if (v < TILE_VECS) stg[i] = gsrc[v];
    }
}

__device__ __forceinline__ void handoff_tile(float* sb, int t, const vfloat4* stg) {
    vfloat4* sv = reinterpret_cast<vfloat4*>(sb);
    #pragma unroll
    for (int i = 0; i < VEC_ITERS; ++i) {
        const int v = i * THREADS + t;
        if (v < TILE_VECS) sv[v] = stg[i];
    }
}

__device__ __forceinline__ void writeout_tile(float* __restrict__ out,
                                              int tile, int t, const float* sb) {
    vfloat4* dst = reinterpret_cast<vfloat4*>(out + (size_t)tile * TILE_FLOATS);
    const vfloat4* sv = reinterpret_cast<const vfloat4*>(sb);
    #pragma unroll
    for (int i = 0; i < VEC_ITERS; ++i) {
        const int v = i * THREADS + t;
        if (v < TILE_VECS) __builtin_nontemporal_store(sv[v], &dst[v]);
    }
}

__device__ __forceinline__ void compute_row(float* sb, int t, float rr, float dn) {
    const float c = 0.9f * (1.0f - dn);                      // exactly 0.9 or 0.0
    const float base = fmaf(-16.66666667f, c, (rr + 40.0f) * (1.0f / 2.4f));
    const int ib = t * ATOMS;

    float p[ATOMS];
    #pragma unroll
    for (int j = 0; j < ATOMS; ++j) p[j] = sb[ib + j];

    // zero whole tile, flat b128 (DS pipe in-order after the reads above)
    {
        vfloat4* sv = reinterpret_cast<vfloat4*>(sb);
        const vfloat4 z = {0.f, 0.f, 0.f, 0.f};
        #pragma unroll
        for (int i = 0; i < VEC_ITERS; ++i) {
            const int v = i * THREADS + t;
            if (v < TILE_VECS) sv[v] = z;
        }
    }

    // scatter-free streaming emit (l_j advances by 0 or 1; c < 1)
    int   cur  = (int)floorf(fminf(fmaxf(base, 0.0f), 50.0f));
    float vcur = 0.0f, vnext = 0.0f;
    #pragma unroll
    for (int j = 0; j < ATOMS; ++j) {
        float b = fmaf(c, (float)j, base);
        b = fminf(fmaxf(b, 0.0f), 50.0f);
        const float lf = floorf(b);
        const float f  = b - lf;
        const int  li  = (int)lf;
        if (li > cur) {
            sb[ib + cur] = vcur;
            vcur = vnext; vnext = 0.0f; ++cur;
        }
        vcur  = fmaf(1.0f - f, p[j], vcur);
        vnext = fmaf(f,        p[j], vnext);
    }
    sb[ib + cur] = vcur;
    if (cur < ATOMS - 1) sb[ib + cur + 1] = vnext;
}

__global__ __launch_bounds__(THREADS) void c51_project(
    const float* __restrict__ prob,
    const float* __restrict__ rin,
    const float* __restrict__ done,
    float* __restrict__ out,
    int nrows)
{
    __shared__ __align__(16) float s_buf[TILE_FLOATS];
    const int t = threadIdx.x;
    const int G = gridDim.x;
    const int ntiles = nrows / RPB;
    const int tail_rows = nrows - ntiles * RPB;

    int tk = blockIdx.x;
    if (tk < ntiles) {
        vfloat4 stgA[VEC_ITERS], stgB[VEC_ITERS];
        float rA = 0.f, dA = 0.f, rB = 0.f, dB = 0.f;

        // prologue: tiles tk -> A, tk+G -> B
        load_tile(prob, tk, t, stgA);
        rA = rin[(size_t)tk * RPB + t];
        dA = done[(size_t)tk * RPB + t];
        if (tk + G < ntiles) {
            load_tile(prob, tk + G, t, stgB);
            rB = rin[(size_t)(tk + G) * RPB + t];
            dB = done[(size_t)(tk + G) * RPB + t];
        }

        for (; tk < ntiles; tk += 2 * G) {
            // ---- half-body A: tile tk ----
            {
                handoff_tile(s_buf, t, stgA);
                const int pf = tk + 2 * G;
                float rnx = 0.f, dnx = 0.f;
                if (pf < ntiles) {
                    load_tile(prob, pf, t, stgA);
                    rnx = rin[(size_t)pf * RPB + t];
                    dnx = done[(size_t)pf * RPB + t];
                }
                __builtin_amdgcn_sched_barrier(0);
                compute_row(s_buf, t, rA, dA);
                writeout_tile(out, tk, t, s_buf);
                rA = rnx; dA = dnx;
            }
            // ---- half-body B: tile tk+G ----
            const int tkB = tk + G;
            if (tkB < ntiles) {
                handoff_tile(s_buf, t, stgB);
                const int pf = tkB + 2 * G;
                float rnx = 0.f, dnx = 0.f;
                if (pf < ntiles) {
                    load_tile(prob, pf, t, stgB);
                    rnx = rin[(size_t)pf * RPB + t];
                    dnx = done[(size_t)pf * RPB + t];
                }
                __builtin_amdgcn_sched_barrier(0);
                compute_row(s_buf, t, rB, dB);
                writeout_tile(out, tkB, t, s_buf);
                rB = rnx; dB = dnx;
            }
        }
    }

    // ---- tail tile (nrows % 64) — block 0, plain path ----
    if (tail_rows > 0 && blockIdx.x == 0) {
        const long long row0 = (long long)ntiles * RPB;
        const int n_e = tail_rows * ATOMS;
        const float* gsrc = prob + (size_t)row0 * ATOMS;
        __syncthreads();
        for (int e = t; e < n_e; e += THREADS) s_buf[e] = gsrc[e];
        __syncthreads();
        if (t < tail_rows) compute_row(s_buf, t, rin[row0 + t], done[row0 + t]);
        __syncthreads();
        float* dst = out + (size_t)row0 * ATOMS;
        for (int e = t; e < n_e; e += THREADS) dst[e] = s_buf[e];
    }
}

extern "C" void kernel_launch(void* const* d_in, const int* in_sizes, int n_in,
                              void* d_out, int out_size, void* d_ws, size_t ws_size,
                              hipStream_t stream) {
    const float* prob = (const float*)d_in[0];
    const float* r    = (const float*)d_in[1];
    const float* done = (const float*)d_in[2];
    float* outp = (float*)d_out;
    const int B = in_sizes[1];               // r: [B,1]
    const int ntiles = B / RPB;
    int grid = ntiles < GRID_MAX ? ntiles : GRID_MAX;
    if (grid < 1) grid = 1;
    c51_project<<<dim3(grid), dim3(THREADS), 0, stream>>>(prob, r, done, outp, B);
}